// Round 7
// baseline (525.142 us; speedup 1.0000x reference)
//
#include <hip/hip_runtime.h>
#include <stdint.h>

// Problem dims (fixed)
#define BB 64
#define TT 32
#define EE 512
#define HH 512
#define VV 32000
#define G4 2048

typedef _Float16 f16x8 __attribute__((ext_vector_type(8)));
typedef float f32x4 __attribute__((ext_vector_type(4)));

__device__ __forceinline__ unsigned short f2h(float f) {
  return __builtin_bit_cast(unsigned short, (_Float16)f);   // RNE hw cvt
}
__device__ __forceinline__ void gload_lds16(const unsigned short* g, unsigned short* l) {
  __builtin_amdgcn_global_load_lds((const __attribute__((address_space(1))) void*)g,
                                   (__attribute__((address_space(3))) void*)l, 16, 0, 0);
}
__device__ __forceinline__ float sigm(float x) { return 1.f / (1.f + __expf(-x)); }
__device__ __forceinline__ float tanh_fast(float x) {
  return 1.f - 2.f / (__expf(2.f * x) + 1.f);   // stable at +-inf
}

// ---------------------------------------------------------------------------
// Kernel 1: Gpre(2112 x 2048) = [feat; emb[cap]] @ W_ih.T + (b_ih + b_hh) [fp32]
// (unchanged, verified r2-r6)
// ---------------------------------------------------------------------------
__global__ __launch_bounds__(256) void k_gemm_ih(const float* __restrict__ feat,
                                                 const int* __restrict__ cap,
                                                 const float* __restrict__ emb,
                                                 const float* __restrict__ Bw,
                                                 const float* __restrict__ bih,
                                                 const float* __restrict__ bhh,
                                                 float* __restrict__ C) {
  __shared__ float As[16][128];
  __shared__ float Bs[16][128];
  const int tid = threadIdx.x;
  const int bx = blockIdx.x & 15;   // n tile 0..15
  const int by = blockIdx.x >> 4;   // m tile 0..16
  const int m0 = by * 128, n0 = bx * 128;
  const int tx = tid & 15, ty = tid >> 4;

  float acc[8][8];
#pragma unroll
  for (int i = 0; i < 8; i++)
#pragma unroll
    for (int j = 0; j < 8; j++) acc[i][j] = 0.f;

  const int lr = tid >> 1;           // row-in-tile 0..127
  const int lk = (tid & 1) * 8;      // 0 or 8
  int arow = m0 + lr; if (arow > 2111) arow = 2111;  // clamp (store guarded)
  const float* Ap;
  if (arow < BB) {
    Ap = feat + (size_t)arow * EE + lk;
  } else {
    int idx = arow - BB;
    int t = idx >> 6, b = idx & 63;
    Ap = emb + (size_t)cap[b * TT + t] * EE + lk;
  }
  const int brow = n0 + lr;          // < 2048 always
  const float* Bp = Bw + (size_t)brow * EE + lk;

  for (int k0 = 0; k0 < EE; k0 += 16) {
    float4 a0 = *(const float4*)(Ap + k0);
    float4 a1 = *(const float4*)(Ap + k0 + 4);
    float4 b0 = *(const float4*)(Bp + k0);
    float4 b1 = *(const float4*)(Bp + k0 + 4);
    __syncthreads();
    As[lk + 0][lr] = a0.x; As[lk + 1][lr] = a0.y; As[lk + 2][lr] = a0.z; As[lk + 3][lr] = a0.w;
    As[lk + 4][lr] = a1.x; As[lk + 5][lr] = a1.y; As[lk + 6][lr] = a1.z; As[lk + 7][lr] = a1.w;
    Bs[lk + 0][lr] = b0.x; Bs[lk + 1][lr] = b0.y; Bs[lk + 2][lr] = b0.z; Bs[lk + 3][lr] = b0.w;
    Bs[lk + 4][lr] = b1.x; Bs[lk + 5][lr] = b1.y; Bs[lk + 6][lr] = b1.z; Bs[lk + 7][lr] = b1.w;
    __syncthreads();
#pragma unroll
    for (int k = 0; k < 16; k++) {
      float a[8], b[8];
      *(float4*)&a[0] = *(const float4*)&As[k][ty * 8];
      *(float4*)&a[4] = *(const float4*)&As[k][ty * 8 + 4];
      *(float4*)&b[0] = *(const float4*)&Bs[k][tx * 8];
      *(float4*)&b[4] = *(const float4*)&Bs[k][tx * 8 + 4];
#pragma unroll
      for (int i = 0; i < 8; i++)
#pragma unroll
        for (int j = 0; j < 8; j++) acc[i][j] += a[i] * b[j];
    }
  }

  float bs[8];
#pragma unroll
  for (int j = 0; j < 8; j++) {
    int n = n0 + tx * 8 + j;
    bs[j] = bih[n] + bhh[n];
  }
#pragma unroll
  for (int i = 0; i < 8; i++) {
    int m = m0 + ty * 8 + i;
    if (m < 2112) {
      float4 o0, o1;
      o0.x = acc[i][0] + bs[0]; o0.y = acc[i][1] + bs[1];
      o0.z = acc[i][2] + bs[2]; o0.w = acc[i][3] + bs[3];
      o1.x = acc[i][4] + bs[4]; o1.y = acc[i][5] + bs[5];
      o1.z = acc[i][6] + bs[6]; o1.w = acc[i][7] + bs[7];
      *(float4*)(C + (size_t)m * G4 + n0 + tx * 8) = o0;
      *(float4*)(C + (size_t)m * G4 + n0 + tx * 8 + 4) = o1;
    }
  }
}

// ---------------------------------------------------------------------------
// Kernel 2: cast W_out f32 -> fp16 (bits in ushort)
// ---------------------------------------------------------------------------
__global__ void k_cast(const float* __restrict__ src, unsigned short* __restrict__ dst, int n4) {
  int i = blockIdx.x * blockDim.x + threadIdx.x;
  int stride = gridDim.x * blockDim.x;
  for (; i < n4; i += stride) {
    float4 v = ((const float4*)src)[i];
    ushort4 o;
    o.x = f2h(v.x); o.y = f2h(v.y); o.z = f2h(v.z); o.w = f2h(v.w);
    ((ushort4*)dst)[i] = o;
  }
}

// ---------------------------------------------------------------------------
// Kernel 3: zero the 33 per-step arrival counters (every call: replay-safe)
// ---------------------------------------------------------------------------
__global__ void k_zero(int* ctr) {
  if (threadIdx.x < 33)
    __hip_atomic_store(&ctr[threadIdx.x], 0, __ATOMIC_RELAXED, __HIP_MEMORY_SCOPE_AGENT);
}

// ---------------------------------------------------------------------------
// Kernel 4: FUSED persistent recurrence + out-projection.
// 256 blocks x 512 thr, all co-resident (64KB LDS, 8 waves).
// Blocks 0..63 (rnn role): r6's proven step body; h stored to hseq[s] as
//   packed u32 agent atomics; arrival = atomicAdd(ctr[s]); 1-lane poll.
//   They never wait on out blocks -> deadlock-free, pipeline producer.
// Blocks 64..255 (out role): per step poll ctr[s]==64, stage h_s (64KB) to
//   LDS (gload_lds, inverse-swizzled source), compute 1-2 vocab slices of
//   128 cols vs W_out (L2-resident per block after step 1), float4 stores.
// hseq[s] plain-load only after ctr[s] reaches 64 this call (ctr zeroed by
// k_zero each call; stale-L2-line discipline proven r3-r6).
// ---------------------------------------------------------------------------
__global__ __launch_bounds__(512) void k_fused(const float* __restrict__ Gpre,
                                               const float* __restrict__ Whh,
                                               const unsigned short* __restrict__ Wb,
                                               const float* __restrict__ bout,
                                               char* hseq_base,
                                               float* __restrict__ out,
                                               int* __restrict__ ctr) {
  __shared__ __align__(16) char lds_raw[65536];
  unsigned short* hseq16 = (unsigned short*)hseq_base;
  unsigned int* hseq32 = (unsigned int*)hseq_base;

  const int tid = threadIdx.x;
  const int bid = blockIdx.x;
  const int l = tid & 63;
  const int w = tid >> 6;

  if (bid < 64) {
    // ======================= RNN role =======================
    unsigned short* W_lds = (unsigned short*)lds_raw;        // 32 KB
    float* gate_buf = (float*)(lds_raw + 32768);             // 8 KB
    const int u0 = bid * 8;
    const int lr = l & 15;
    const int kc = l >> 4;
    const int nt = w & 1;
    const int mt = w >> 1;
    const int es = w * 8 + (l >> 3);
    const int edu = l & 7;

    // stage W_hh (f32 -> fp16) into LDS, chunk-XOR swizzled
    {
      int row = tid >> 4;            // 0..31 (= g*8 + du)
      int sub = tid & 15;
      int g = row >> 3, du = row & 7;
      const float* srcp = Whh + (size_t)(g * 512 + u0 + du) * HH;
#pragma unroll
      for (int c0 = 0; c0 < 4; ++c0) {
        int c = sub * 4 + c0;
        float4 va = *(const float4*)(srcp + c * 8);
        float4 vb = *(const float4*)(srcp + c * 8 + 4);
        __align__(16) unsigned short t8[8];
        t8[0] = f2h(va.x); t8[1] = f2h(va.y); t8[2] = f2h(va.z); t8[3] = f2h(va.w);
        t8[4] = f2h(vb.x); t8[5] = f2h(vb.y); t8[6] = f2h(vb.z); t8[7] = f2h(vb.w);
        *(int4*)((char*)W_lds + row * 1024 + ((c ^ (row & 7)) * 16)) = *(const int4*)t8;
      }
    }

    // prime (h=c=0)
    float c_reg;
    {
      const float* gp = Gpre + (size_t)es * G4 + u0 + edu;
      float gi = gp[0], gg = gp[1024], go = gp[1536];
      float cn = sigm(gi) * tanh_fast(gg);
      float hn = sigm(go) * tanh_fast(cn);
      c_reg = cn;
      unsigned int hb = f2h(hn);
      unsigned int other = (unsigned int)__shfl_xor((int)hb, 1);
      if (!(l & 1))
        __hip_atomic_store(&hseq32[(size_t)es * 256 + bid * 4 + (edu >> 1)],
                           hb | (other << 16), __ATOMIC_RELAXED, __HIP_MEMORY_SCOPE_AGENT);
    }
    asm volatile("s_waitcnt vmcnt(0)" ::: "memory");
    __syncthreads();
    if (tid == 0)
      __hip_atomic_fetch_add(&ctr[0], 1, __ATOMIC_RELAXED, __HIP_MEMORY_SCOPE_AGENT);

    float pre[4];
#pragma unroll
    for (int g = 0; g < 4; ++g)
      pre[g] = Gpre[((size_t)64 + es) * G4 + g * 512 + u0 + edu];

    if (tid == 0) {
      while (__hip_atomic_load(&ctr[0], __ATOMIC_RELAXED, __HIP_MEMORY_SCOPE_AGENT) < 64)
        __builtin_amdgcn_s_sleep(1);
    }
    __syncthreads();

    for (int s = 1; s <= TT; ++s) {
      const unsigned short* hin = hseq16 + (size_t)(s - 1) * BB * HH;
      f32x4 acca = {0.f, 0.f, 0.f, 0.f};
      f32x4 accb = {0.f, 0.f, 0.f, 0.f};
      const unsigned short* hbase = hin + (size_t)(mt * 16 + lr) * HH + kc * 8;
      const int wrow = nt * 16 + lr;
      const char* wbase = (const char*)W_lds + wrow * 1024;
#pragma unroll
      for (int kk = 0; kk < 8; ++kk) {
        uint4 hq0 = *(const uint4*)(hbase + kk * 32);
        int4 wq0 = *(const int4*)(wbase + (((kk * 4 + kc) ^ (wrow & 7)) * 16));
        acca = __builtin_amdgcn_mfma_f32_16x16x32_f16(
            __builtin_bit_cast(f16x8, hq0), __builtin_bit_cast(f16x8, wq0), acca, 0, 0, 0);
        uint4 hq1 = *(const uint4*)(hbase + (kk + 8) * 32);
        int4 wq1 = *(const int4*)(wbase + ((((kk + 8) * 4 + kc) ^ (wrow & 7)) * 16));
        accb = __builtin_amdgcn_mfma_f32_16x16x32_f16(
            __builtin_bit_cast(f16x8, hq1), __builtin_bit_cast(f16x8, wq1), accb, 0, 0, 0);
      }
      f32x4 acc;
#pragma unroll
      for (int j = 0; j < 4; ++j) acc[j] = acca[j] + accb[j];

      // gate partials -> LDS (XOR-swizzled on sample index)
      {
        int g = nt * 2 + (lr >> 3);
        int du = lr & 7;
#pragma unroll
        for (int j = 0; j < 4; ++j) {
          int ss = mt * 16 + kc * 4 + j;
          gate_buf[g * 512 + du * 64 + (ss ^ (du << 3))] = acc[j];
        }
      }
      __syncthreads();

      // epilogue: one (es, edu) update per thread
      {
        float gi = gate_buf[0 * 512 + edu * 64 + (es ^ (edu << 3))] + pre[0];
        float gf = gate_buf[1 * 512 + edu * 64 + (es ^ (edu << 3))] + pre[1];
        float gg = gate_buf[2 * 512 + edu * 64 + (es ^ (edu << 3))] + pre[2];
        float go = gate_buf[3 * 512 + edu * 64 + (es ^ (edu << 3))] + pre[3];
        float cn = sigm(gf) * c_reg + sigm(gi) * tanh_fast(gg);
        float hn = sigm(go) * tanh_fast(cn);
        c_reg = cn;
        unsigned int hb = f2h(hn);
        unsigned int other = (unsigned int)__shfl_xor((int)hb, 1);
        if (!(l & 1))
          __hip_atomic_store(&hseq32[(size_t)s * 16384 + es * 256 + bid * 4 + (edu >> 1)],
                             hb | (other << 16), __ATOMIC_RELAXED, __HIP_MEMORY_SCOPE_AGENT);
      }
      asm volatile("s_waitcnt vmcnt(0)" ::: "memory");
      __syncthreads();
      if (tid == 0)
        __hip_atomic_fetch_add(&ctr[s], 1, __ATOMIC_RELAXED, __HIP_MEMORY_SCOPE_AGENT);

      if (s < TT) {
#pragma unroll
        for (int g = 0; g < 4; ++g)
          pre[g] = Gpre[((size_t)(s + 1) * 64 + es) * G4 + g * 512 + u0 + edu];
        if (tid == 0) {
          while (__hip_atomic_load(&ctr[s], __ATOMIC_RELAXED, __HIP_MEMORY_SCOPE_AGENT) < 64)
            __builtin_amdgcn_s_sleep(1);
        }
        __syncthreads();
      }
    }
  } else {
    // ======================= OUT role =======================
    unsigned short* As = (unsigned short*)lds_raw;           // 64 KB: h_s staged
    const int slice0 = bid - 64;           // 0..191
    const bool two = (slice0 < 58);        // slices 192..249
    const int n00 = slice0 * 128;
    const int n01 = (two ? (slice0 + 192) : slice0) * 128;
    const int bcol = w * 16 + (l >> 4) * 4;
    const float4 bo0 = *(const float4*)(bout + n00 + bcol);
    const float4 bo1 = *(const float4*)(bout + n01 + bcol);

    for (int s = 1; s <= TT; ++s) {
      if (tid == 0) {
        while (__hip_atomic_load(&ctr[s], __ATOMIC_RELAXED, __HIP_MEMORY_SCOPE_AGENT) < 64)
          __builtin_amdgcn_s_sleep(4);
      }
      __syncthreads();   // release block; also guards As reuse from prev step

      // stage h_s (64 x 512 fp16 = 64 KB) -> LDS, inverse-swizzled source
      const unsigned short* hs = hseq16 + (size_t)s * BB * HH;
#pragma unroll
      for (int it = 0; it < 8; ++it) {
        int ci = it * 512 + tid;           // 16B-chunk index 0..4095
        int row = ci >> 6, cd = ci & 63;
        gload_lds16(hs + (size_t)row * 512 + (cd ^ (row & 7)) * 8, As + ci * 8);
      }
      asm volatile("s_waitcnt vmcnt(0)" ::: "memory");
      __syncthreads();

#pragma unroll
      for (int sl = 0; sl < 2; ++sl) {
        if (sl == 1 && !two) break;
        const int n0 = sl ? n01 : n00;
        const float4 bo = sl ? bo1 : bo0;
        const unsigned short* Bbase = Wb + (size_t)(n0 + w * 16 + (l & 15)) * 512 + (l >> 4) * 8;
        f32x4 acc[4];
#pragma unroll
        for (int m = 0; m < 4; ++m) acc[m] = (f32x4){0.f, 0.f, 0.f, 0.f};
#pragma unroll
        for (int kt = 0; kt < 16; ++kt) {
          uint4 bq = *(const uint4*)(Bbase + kt * 32);
          f16x8 bf = __builtin_bit_cast(f16x8, bq);
#pragma unroll
          for (int m = 0; m < 4; ++m) {
            int row = m * 16 + (l & 15);
            int c = kt * 4 + (l >> 4);
            f16x8 af = *(const f16x8*)&As[row * 512 + (c ^ (row & 7)) * 8];
            // swapped operands: result col(lane&15) = A-row (sample),
            // row-field = B-row (vocab) -> lane stores 4 consecutive cols
            acc[m] = __builtin_amdgcn_mfma_f32_16x16x32_f16(bf, af, acc[m], 0, 0, 0);
          }
        }
#pragma unroll
        for (int m = 0; m < 4; ++m) {
          int b = m * 16 + (l & 15);
          float* orow = out + ((size_t)(b * TT + (s - 1))) * VV + n0 + bcol;
          float4 v;
          v.x = acc[m][0] + bo.x;
          v.y = acc[m][1] + bo.y;
          v.z = acc[m][2] + bo.z;
          v.w = acc[m][3] + bo.w;
          *(float4*)orow = v;
        }
      }
    }
  }
}

// ---------------------------------------------------------------------------
extern "C" void kernel_launch(void* const* d_in, const int* in_sizes, int n_in,
                              void* d_out, int out_size, void* d_ws, size_t ws_size,
                              hipStream_t stream) {
  const float* feat = (const float*)d_in[0];
  const int* cap = (const int*)d_in[1];
  // d_in[2] = seq_len (constant 32)
  const float* emb = (const float*)d_in[3];
  const float* Wih = (const float*)d_in[4];
  const float* Whh = (const float*)d_in[5];
  const float* bih = (const float*)d_in[6];
  const float* bhh = (const float*)d_in[7];
  const float* Wout = (const float*)d_in[8];
  const float* bout = (const float*)d_in[9];
  float* out = (float*)d_out;

  char* ws = (char*)d_ws;
  float* Gpre = (float*)ws;                                   // 17,301,504
  unsigned short* Wb = (unsigned short*)(ws + 17301504);      // 32,768,000 (fp16)
  char* hseq = ws + 50069504;                                 //  2,162,688 (33 x 64 x 512 fp16)
  int* ctr = (int*)(ws + 52232192);                           //        132

  k_zero<<<dim3(1), dim3(64), 0, stream>>>(ctr);
  k_gemm_ih<<<dim3(17 * 16), dim3(256), 0, stream>>>(feat, cap, emb, Wih, bih, bhh, Gpre);
  k_cast<<<dim3(2048), dim3(256), 0, stream>>>(Wout, Wb, (VV * HH) / 4);
  k_fused<<<dim3(256), dim3(512), 0, stream>>>(Gpre, Whh, Wb, bout, hseq, out, ctr);
}

// Round 8
// 454.076 us; speedup vs baseline: 1.1565x; 1.1565x over previous
//
#include <hip/hip_runtime.h>
#include <stdint.h>

// Problem dims (fixed)
#define BB 64
#define TT 32
#define EE 512
#define HH 512
#define VV 32000
#define G4 2048

typedef _Float16 f16x8 __attribute__((ext_vector_type(8)));
typedef float f32x4 __attribute__((ext_vector_type(4)));

__device__ __forceinline__ unsigned short f2h(float f) {
  return __builtin_bit_cast(unsigned short, (_Float16)f);   // RNE hw cvt
}
__device__ __forceinline__ void gload_lds16(const unsigned short* g, unsigned short* l) {
  __builtin_amdgcn_global_load_lds((const __attribute__((address_space(1))) void*)g,
                                   (__attribute__((address_space(3))) void*)l, 16, 0, 0);
}
__device__ __forceinline__ float sigm(float x) { return 1.f / (1.f + __expf(-x)); }
__device__ __forceinline__ float tanh_fast(float x) {
  return 1.f - 2.f / (__expf(2.f * x) + 1.f);   // stable at +-inf
}

// ---------------------------------------------------------------------------
// Kernel 1: Gpre(2112 x 2048) = [feat; emb[cap]] @ W_ih.T + (b_ih + b_hh) [fp32]
// (unchanged, verified r2-r7)
// ---------------------------------------------------------------------------
__global__ __launch_bounds__(256) void k_gemm_ih(const float* __restrict__ feat,
                                                 const int* __restrict__ cap,
                                                 const float* __restrict__ emb,
                                                 const float* __restrict__ Bw,
                                                 const float* __restrict__ bih,
                                                 const float* __restrict__ bhh,
                                                 float* __restrict__ C) {
  __shared__ float As[16][128];
  __shared__ float Bs[16][128];
  const int tid = threadIdx.x;
  const int bx = blockIdx.x & 15;   // n tile 0..15
  const int by = blockIdx.x >> 4;   // m tile 0..16
  const int m0 = by * 128, n0 = bx * 128;
  const int tx = tid & 15, ty = tid >> 4;

  float acc[8][8];
#pragma unroll
  for (int i = 0; i < 8; i++)
#pragma unroll
    for (int j = 0; j < 8; j++) acc[i][j] = 0.f;

  const int lr = tid >> 1;           // row-in-tile 0..127
  const int lk = (tid & 1) * 8;      // 0 or 8
  int arow = m0 + lr; if (arow > 2111) arow = 2111;  // clamp (store guarded)
  const float* Ap;
  if (arow < BB) {
    Ap = feat + (size_t)arow * EE + lk;
  } else {
    int idx = arow - BB;
    int t = idx >> 6, b = idx & 63;
    Ap = emb + (size_t)cap[b * TT + t] * EE + lk;
  }
  const int brow = n0 + lr;          // < 2048 always
  const float* Bp = Bw + (size_t)brow * EE + lk;

  for (int k0 = 0; k0 < EE; k0 += 16) {
    float4 a0 = *(const float4*)(Ap + k0);
    float4 a1 = *(const float4*)(Ap + k0 + 4);
    float4 b0 = *(const float4*)(Bp + k0);
    float4 b1 = *(const float4*)(Bp + k0 + 4);
    __syncthreads();
    As[lk + 0][lr] = a0.x; As[lk + 1][lr] = a0.y; As[lk + 2][lr] = a0.z; As[lk + 3][lr] = a0.w;
    As[lk + 4][lr] = a1.x; As[lk + 5][lr] = a1.y; As[lk + 6][lr] = a1.z; As[lk + 7][lr] = a1.w;
    Bs[lk + 0][lr] = b0.x; Bs[lk + 1][lr] = b0.y; Bs[lk + 2][lr] = b0.z; Bs[lk + 3][lr] = b0.w;
    Bs[lk + 4][lr] = b1.x; Bs[lk + 5][lr] = b1.y; Bs[lk + 6][lr] = b1.z; Bs[lk + 7][lr] = b1.w;
    __syncthreads();
#pragma unroll
    for (int k = 0; k < 16; k++) {
      float a[8], b[8];
      *(float4*)&a[0] = *(const float4*)&As[k][ty * 8];
      *(float4*)&a[4] = *(const float4*)&As[k][ty * 8 + 4];
      *(float4*)&b[0] = *(const float4*)&Bs[k][tx * 8];
      *(float4*)&b[4] = *(const float4*)&Bs[k][tx * 8 + 4];
#pragma unroll
      for (int i = 0; i < 8; i++)
#pragma unroll
        for (int j = 0; j < 8; j++) acc[i][j] += a[i] * b[j];
    }
  }

  float bs[8];
#pragma unroll
  for (int j = 0; j < 8; j++) {
    int n = n0 + tx * 8 + j;
    bs[j] = bih[n] + bhh[n];
  }
#pragma unroll
  for (int i = 0; i < 8; i++) {
    int m = m0 + ty * 8 + i;
    if (m < 2112) {
      float4 o0, o1;
      o0.x = acc[i][0] + bs[0]; o0.y = acc[i][1] + bs[1];
      o0.z = acc[i][2] + bs[2]; o0.w = acc[i][3] + bs[3];
      o1.x = acc[i][4] + bs[4]; o1.y = acc[i][5] + bs[5];
      o1.z = acc[i][6] + bs[6]; o1.w = acc[i][7] + bs[7];
      *(float4*)(C + (size_t)m * G4 + n0 + tx * 8) = o0;
      *(float4*)(C + (size_t)m * G4 + n0 + tx * 8 + 4) = o1;
    }
  }
}

// ---------------------------------------------------------------------------
// Kernel 2: zero the 33 per-step arrival counters (every call: replay-safe)
// ---------------------------------------------------------------------------
__global__ void k_zero(int* ctr) {
  if (threadIdx.x < 33)
    __hip_atomic_store(&ctr[threadIdx.x], 0, __ATOMIC_RELAXED, __HIP_MEMORY_SCOPE_AGENT);
}

// ---------------------------------------------------------------------------
// Kernel 3: FUSED persistent recurrence + out-projection.
// 256 blocks x 512 thr, all co-resident.
// Blocks 0..63 (rnn role): unchanged r7 step body (W_hh fp16 in LDS, 16 MFMA,
//   gate_buf combine, c in regs, packed-u32 agent-atomic h stores to hseq[s],
//   arrival = atomicAdd(ctr[s]), 1-lane poll). Never waits on out blocks.
// Blocks 64..255 (out role): W_out slice(s) preloaded ONCE f32->f16 into
//   REGISTERS (64 VGPR per 128-col slice; 58 blocks hold 2 slices = 250 total)
//   -- eliminates r7's 531MB per-step W re-fetch (L2 thrash). Per step: poll
//   ctr[s]==64, stage h_s 64KB -> LDS (gload_lds, inverse-swizzled source),
//   LDS(h) x regs(W) MFMAs, swapped operands -> float4 stores.
// ---------------------------------------------------------------------------
__global__ __launch_bounds__(512) void k_fused(const float* __restrict__ Gpre,
                                               const float* __restrict__ Whh,
                                               const float* __restrict__ Wout,
                                               const float* __restrict__ bout,
                                               char* hseq_base,
                                               float* __restrict__ out,
                                               int* __restrict__ ctr) {
  __shared__ __align__(16) char lds_raw[65536];
  unsigned short* hseq16 = (unsigned short*)hseq_base;
  unsigned int* hseq32 = (unsigned int*)hseq_base;

  const int tid = threadIdx.x;
  const int bid = blockIdx.x;
  const int l = tid & 63;
  const int w = tid >> 6;

  if (bid < 64) {
    // ======================= RNN role =======================
    unsigned short* W_lds = (unsigned short*)lds_raw;        // 32 KB
    float* gate_buf = (float*)(lds_raw + 32768);             // 8 KB
    const int u0 = bid * 8;
    const int lr = l & 15;
    const int kc = l >> 4;
    const int nt = w & 1;
    const int mt = w >> 1;
    const int es = w * 8 + (l >> 3);
    const int edu = l & 7;

    // stage W_hh (f32 -> fp16) into LDS, chunk-XOR swizzled
    {
      int row = tid >> 4;            // 0..31 (= g*8 + du)
      int sub = tid & 15;
      int g = row >> 3, du = row & 7;
      const float* srcp = Whh + (size_t)(g * 512 + u0 + du) * HH;
#pragma unroll
      for (int c0 = 0; c0 < 4; ++c0) {
        int c = sub * 4 + c0;
        float4 va = *(const float4*)(srcp + c * 8);
        float4 vb = *(const float4*)(srcp + c * 8 + 4);
        __align__(16) unsigned short t8[8];
        t8[0] = f2h(va.x); t8[1] = f2h(va.y); t8[2] = f2h(va.z); t8[3] = f2h(va.w);
        t8[4] = f2h(vb.x); t8[5] = f2h(vb.y); t8[6] = f2h(vb.z); t8[7] = f2h(vb.w);
        *(int4*)((char*)W_lds + row * 1024 + ((c ^ (row & 7)) * 16)) = *(const int4*)t8;
      }
    }

    // prime (h=c=0)
    float c_reg;
    {
      const float* gp = Gpre + (size_t)es * G4 + u0 + edu;
      float gi = gp[0], gg = gp[1024], go = gp[1536];
      float cn = sigm(gi) * tanh_fast(gg);
      float hn = sigm(go) * tanh_fast(cn);
      c_reg = cn;
      unsigned int hb = f2h(hn);
      unsigned int other = (unsigned int)__shfl_xor((int)hb, 1);
      if (!(l & 1))
        __hip_atomic_store(&hseq32[(size_t)es * 256 + bid * 4 + (edu >> 1)],
                           hb | (other << 16), __ATOMIC_RELAXED, __HIP_MEMORY_SCOPE_AGENT);
    }
    asm volatile("s_waitcnt vmcnt(0)" ::: "memory");
    __syncthreads();
    if (tid == 0)
      __hip_atomic_fetch_add(&ctr[0], 1, __ATOMIC_RELAXED, __HIP_MEMORY_SCOPE_AGENT);

    float pre[4];
#pragma unroll
    for (int g = 0; g < 4; ++g)
      pre[g] = Gpre[((size_t)64 + es) * G4 + g * 512 + u0 + edu];

    if (tid == 0) {
      while (__hip_atomic_load(&ctr[0], __ATOMIC_RELAXED, __HIP_MEMORY_SCOPE_AGENT) < 64)
        __builtin_amdgcn_s_sleep(1);
    }
    __syncthreads();

    for (int s = 1; s <= TT; ++s) {
      const unsigned short* hin = hseq16 + (size_t)(s - 1) * BB * HH;
      f32x4 acca = {0.f, 0.f, 0.f, 0.f};
      f32x4 accb = {0.f, 0.f, 0.f, 0.f};
      const unsigned short* hbase = hin + (size_t)(mt * 16 + lr) * HH + kc * 8;
      const int wrow = nt * 16 + lr;
      const char* wbase = (const char*)W_lds + wrow * 1024;
#pragma unroll
      for (int kk = 0; kk < 8; ++kk) {
        uint4 hq0 = *(const uint4*)(hbase + kk * 32);
        int4 wq0 = *(const int4*)(wbase + (((kk * 4 + kc) ^ (wrow & 7)) * 16));
        acca = __builtin_amdgcn_mfma_f32_16x16x32_f16(
            __builtin_bit_cast(f16x8, hq0), __builtin_bit_cast(f16x8, wq0), acca, 0, 0, 0);
        uint4 hq1 = *(const uint4*)(hbase + (kk + 8) * 32);
        int4 wq1 = *(const int4*)(wbase + ((((kk + 8) * 4 + kc) ^ (wrow & 7)) * 16));
        accb = __builtin_amdgcn_mfma_f32_16x16x32_f16(
            __builtin_bit_cast(f16x8, hq1), __builtin_bit_cast(f16x8, wq1), accb, 0, 0, 0);
      }
      f32x4 acc;
#pragma unroll
      for (int j = 0; j < 4; ++j) acc[j] = acca[j] + accb[j];

      // gate partials -> LDS (XOR-swizzled on sample index)
      {
        int g = nt * 2 + (lr >> 3);
        int du = lr & 7;
#pragma unroll
        for (int j = 0; j < 4; ++j) {
          int ss = mt * 16 + kc * 4 + j;
          gate_buf[g * 512 + du * 64 + (ss ^ (du << 3))] = acc[j];
        }
      }
      __syncthreads();

      // epilogue: one (es, edu) update per thread
      {
        float gi = gate_buf[0 * 512 + edu * 64 + (es ^ (edu << 3))] + pre[0];
        float gf = gate_buf[1 * 512 + edu * 64 + (es ^ (edu << 3))] + pre[1];
        float gg = gate_buf[2 * 512 + edu * 64 + (es ^ (edu << 3))] + pre[2];
        float go = gate_buf[3 * 512 + edu * 64 + (es ^ (edu << 3))] + pre[3];
        float cn = sigm(gf) * c_reg + sigm(gi) * tanh_fast(gg);
        float hn = sigm(go) * tanh_fast(cn);
        c_reg = cn;
        unsigned int hb = f2h(hn);
        unsigned int other = (unsigned int)__shfl_xor((int)hb, 1);
        if (!(l & 1))
          __hip_atomic_store(&hseq32[(size_t)s * 16384 + es * 256 + bid * 4 + (edu >> 1)],
                             hb | (other << 16), __ATOMIC_RELAXED, __HIP_MEMORY_SCOPE_AGENT);
      }
      asm volatile("s_waitcnt vmcnt(0)" ::: "memory");
      __syncthreads();
      if (tid == 0)
        __hip_atomic_fetch_add(&ctr[s], 1, __ATOMIC_RELAXED, __HIP_MEMORY_SCOPE_AGENT);

      if (s < TT) {
#pragma unroll
        for (int g = 0; g < 4; ++g)
          pre[g] = Gpre[((size_t)(s + 1) * 64 + es) * G4 + g * 512 + u0 + edu];
        if (tid == 0) {
          while (__hip_atomic_load(&ctr[s], __ATOMIC_RELAXED, __HIP_MEMORY_SCOPE_AGENT) < 64)
            __builtin_amdgcn_s_sleep(1);
        }
        __syncthreads();
      }
    }
  } else {
    // ======================= OUT role =======================
    unsigned short* As = (unsigned short*)lds_raw;           // 64 KB: h_s staged
    const int slice0 = bid - 64;           // 0..191
    const bool two = (slice0 < 58);        // +192 -> slices 192..249
    const int n00 = slice0 * 128;
    const int n01 = (two ? (slice0 + 192) : slice0) * 128;
    const int bcol = w * 16 + (l >> 4) * 4;
    const float4 bo0 = *(const float4*)(bout + n00 + bcol);
    const float4 bo1 = *(const float4*)(bout + n01 + bcol);

    // ---- preload W_out slice(s) f32 -> f16 fragments in REGISTERS (once) ----
    const int vr0 = n00 + w * 16 + (l & 15);
    const int vr1 = n01 + w * 16 + (l & 15);
    const int kb = (l >> 4) * 8;
    uint4 w0r[16], w1r[16];
#pragma unroll
    for (int kt = 0; kt < 16; ++kt) {
      const float* p = Wout + (size_t)vr0 * HH + kt * 32 + kb;
      float4 a = *(const float4*)p;
      float4 b = *(const float4*)(p + 4);
      __align__(16) unsigned short t8[8];
      t8[0] = f2h(a.x); t8[1] = f2h(a.y); t8[2] = f2h(a.z); t8[3] = f2h(a.w);
      t8[4] = f2h(b.x); t8[5] = f2h(b.y); t8[6] = f2h(b.z); t8[7] = f2h(b.w);
      w0r[kt] = *(const uint4*)t8;
    }
    if (two) {
#pragma unroll
      for (int kt = 0; kt < 16; ++kt) {
        const float* p = Wout + (size_t)vr1 * HH + kt * 32 + kb;
        float4 a = *(const float4*)p;
        float4 b = *(const float4*)(p + 4);
        __align__(16) unsigned short t8[8];
        t8[0] = f2h(a.x); t8[1] = f2h(a.y); t8[2] = f2h(a.z); t8[3] = f2h(a.w);
        t8[4] = f2h(b.x); t8[5] = f2h(b.y); t8[6] = f2h(b.z); t8[7] = f2h(b.w);
        w1r[kt] = *(const uint4*)t8;
      }
    }

    for (int s = 1; s <= TT; ++s) {
      if (tid == 0) {
        while (__hip_atomic_load(&ctr[s], __ATOMIC_RELAXED, __HIP_MEMORY_SCOPE_AGENT) < 64)
          __builtin_amdgcn_s_sleep(4);
      }
      __syncthreads();   // release block; also guards As reuse from prev step

      // stage h_s (64 x 512 fp16 = 64 KB) -> LDS, inverse-swizzled source
      const unsigned short* hs = hseq16 + (size_t)s * BB * HH;
#pragma unroll
      for (int it = 0; it < 8; ++it) {
        int ci = it * 512 + tid;           // 16B-chunk index 0..4095
        int row = ci >> 6, cd = ci & 63;
        gload_lds16(hs + (size_t)row * 512 + (cd ^ (row & 7)) * 8, As + ci * 8);
      }
      asm volatile("s_waitcnt vmcnt(0)" ::: "memory");
      __syncthreads();

      f32x4 acc0[4], acc1[4];
#pragma unroll
      for (int m = 0; m < 4; ++m) {
        acc0[m] = (f32x4){0.f, 0.f, 0.f, 0.f};
        acc1[m] = (f32x4){0.f, 0.f, 0.f, 0.f};
      }
#pragma unroll
      for (int m = 0; m < 4; ++m) {
        int row = m * 16 + (l & 15);
#pragma unroll
        for (int kt = 0; kt < 16; ++kt) {
          int c = kt * 4 + (l >> 4);
          f16x8 af = *(const f16x8*)&As[row * 512 + (c ^ (row & 7)) * 8];
          // swapped operands: result col(lane&15) = h-row (sample),
          // row-field = W-row (vocab) -> lane stores 4 consecutive cols
          acc0[m] = __builtin_amdgcn_mfma_f32_16x16x32_f16(
              __builtin_bit_cast(f16x8, w0r[kt]), af, acc0[m], 0, 0, 0);
          if (two)
            acc1[m] = __builtin_amdgcn_mfma_f32_16x16x32_f16(
                __builtin_bit_cast(f16x8, w1r[kt]), af, acc1[m], 0, 0, 0);
        }
      }

#pragma unroll
      for (int m = 0; m < 4; ++m) {
        int b = m * 16 + (l & 15);
        float* orow0 = out + ((size_t)(b * TT + (s - 1))) * VV + n00 + bcol;
        float4 v;
        v.x = acc0[m][0] + bo0.x;
        v.y = acc0[m][1] + bo0.y;
        v.z = acc0[m][2] + bo0.z;
        v.w = acc0[m][3] + bo0.w;
        *(float4*)orow0 = v;
        if (two) {
          float* orow1 = out + ((size_t)(b * TT + (s - 1))) * VV + n01 + bcol;
          float4 v1;
          v1.x = acc1[m][0] + bo1.x;
          v1.y = acc1[m][1] + bo1.y;
          v1.z = acc1[m][2] + bo1.z;
          v1.w = acc1[m][3] + bo1.w;
          *(float4*)orow1 = v1;
        }
      }
    }
  }
}

// ---------------------------------------------------------------------------
extern "C" void kernel_launch(void* const* d_in, const int* in_sizes, int n_in,
                              void* d_out, int out_size, void* d_ws, size_t ws_size,
                              hipStream_t stream) {
  const float* feat = (const float*)d_in[0];
  const int* cap = (const int*)d_in[1];
  // d_in[2] = seq_len (constant 32)
  const float* emb = (const float*)d_in[3];
  const float* Wih = (const float*)d_in[4];
  const float* Whh = (const float*)d_in[5];
  const float* bih = (const float*)d_in[6];
  const float* bhh = (const float*)d_in[7];
  const float* Wout = (const float*)d_in[8];
  const float* bout = (const float*)d_in[9];
  float* out = (float*)d_out;

  char* ws = (char*)d_ws;
  float* Gpre = (float*)ws;                                   // 17,301,504
  char* hseq = ws + 17301504;                                 //  2,162,688 (33 x 64 x 512 fp16)
  int* ctr = (int*)(ws + 19464192);                           //        132

  k_zero<<<dim3(1), dim3(64), 0, stream>>>(ctr);
  k_gemm_ih<<<dim3(17 * 16), dim3(256), 0, stream>>>(feat, cap, emb, Wih, bih, bhh, Gpre);
  k_fused<<<dim3(256), dim3(512), 0, stream>>>(Gpre, Whh, Wout, bout, hseq, out, ctr);
}

// Round 10
// 448.063 us; speedup vs baseline: 1.1720x; 1.0134x over previous
//
#include <hip/hip_runtime.h>
#include <stdint.h>

// Problem dims (fixed)
#define BB 64
#define TT 32
#define EE 512
#define HH 512
#define VV 32000
#define G4 2048

typedef _Float16 f16x8 __attribute__((ext_vector_type(8)));
typedef float f32x4 __attribute__((ext_vector_type(4)));

__device__ __forceinline__ unsigned short f2h(float f) {
  return __builtin_bit_cast(unsigned short, (_Float16)f);   // RNE hw cvt
}
__device__ __forceinline__ void gload_lds16(const unsigned short* g, unsigned short* l) {
  __builtin_amdgcn_global_load_lds((const __attribute__((address_space(1))) void*)g,
                                   (__attribute__((address_space(3))) void*)l, 16, 0, 0);
}
__device__ __forceinline__ float sigm(float x) { return 1.f / (1.f + __expf(-x)); }
__device__ __forceinline__ float tanh_fast(float x) {
  return 1.f - 2.f / (__expf(2.f * x) + 1.f);   // stable at +-inf
}

// ---------------------------------------------------------------------------
// Kernel 1: Gpre(2112 x 2048) = [feat; emb[cap]] @ W_ih.T + (b_ih + b_hh) [fp32]
// (unchanged, verified r2-r8)
// ---------------------------------------------------------------------------
__global__ __launch_bounds__(256) void k_gemm_ih(const float* __restrict__ feat,
                                                 const int* __restrict__ cap,
                                                 const float* __restrict__ emb,
                                                 const float* __restrict__ Bw,
                                                 const float* __restrict__ bih,
                                                 const float* __restrict__ bhh,
                                                 float* __restrict__ C) {
  __shared__ float As[16][128];
  __shared__ float Bs[16][128];
  const int tid = threadIdx.x;
  const int bx = blockIdx.x & 15;   // n tile 0..15
  const int by = blockIdx.x >> 4;   // m tile 0..16
  const int m0 = by * 128, n0 = bx * 128;
  const int tx = tid & 15, ty = tid >> 4;

  float acc[8][8];
#pragma unroll
  for (int i = 0; i < 8; i++)
#pragma unroll
    for (int j = 0; j < 8; j++) acc[i][j] = 0.f;

  const int lr = tid >> 1;           // row-in-tile 0..127
  const int lk = (tid & 1) * 8;      // 0 or 8
  int arow = m0 + lr; if (arow > 2111) arow = 2111;  // clamp (store guarded)
  const float* Ap;
  if (arow < BB) {
    Ap = feat + (size_t)arow * EE + lk;
  } else {
    int idx = arow - BB;
    int t = idx >> 6, b = idx & 63;
    Ap = emb + (size_t)cap[b * TT + t] * EE + lk;
  }
  const int brow = n0 + lr;          // < 2048 always
  const float* Bp = Bw + (size_t)brow * EE + lk;

  for (int k0 = 0; k0 < EE; k0 += 16) {
    float4 a0 = *(const float4*)(Ap + k0);
    float4 a1 = *(const float4*)(Ap + k0 + 4);
    float4 b0 = *(const float4*)(Bp + k0);
    float4 b1 = *(const float4*)(Bp + k0 + 4);
    __syncthreads();
    As[lk + 0][lr] = a0.x; As[lk + 1][lr] = a0.y; As[lk + 2][lr] = a0.z; As[lk + 3][lr] = a0.w;
    As[lk + 4][lr] = a1.x; As[lk + 5][lr] = a1.y; As[lk + 6][lr] = a1.z; As[lk + 7][lr] = a1.w;
    Bs[lk + 0][lr] = b0.x; Bs[lk + 1][lr] = b0.y; Bs[lk + 2][lr] = b0.z; Bs[lk + 3][lr] = b0.w;
    Bs[lk + 4][lr] = b1.x; Bs[lk + 5][lr] = b1.y; Bs[lk + 6][lr] = b1.z; Bs[lk + 7][lr] = b1.w;
    __syncthreads();
#pragma unroll
    for (int k = 0; k < 16; k++) {
      float a[8], b[8];
      *(float4*)&a[0] = *(const float4*)&As[k][ty * 8];
      *(float4*)&a[4] = *(const float4*)&As[k][ty * 8 + 4];
      *(float4*)&b[0] = *(const float4*)&Bs[k][tx * 8];
      *(float4*)&b[4] = *(const float4*)&Bs[k][tx * 8 + 4];
#pragma unroll
      for (int i = 0; i < 8; i++)
#pragma unroll
        for (int j = 0; j < 8; j++) acc[i][j] += a[i] * b[j];
    }
  }

  float bs[8];
#pragma unroll
  for (int j = 0; j < 8; j++) {
    int n = n0 + tx * 8 + j;
    bs[j] = bih[n] + bhh[n];
  }
#pragma unroll
  for (int i = 0; i < 8; i++) {
    int m = m0 + ty * 8 + i;
    if (m < 2112) {
      float4 o0, o1;
      o0.x = acc[i][0] + bs[0]; o0.y = acc[i][1] + bs[1];
      o0.z = acc[i][2] + bs[2]; o0.w = acc[i][3] + bs[3];
      o1.x = acc[i][4] + bs[4]; o1.y = acc[i][5] + bs[5];
      o1.z = acc[i][6] + bs[6]; o1.w = acc[i][7] + bs[7];
      *(float4*)(C + (size_t)m * G4 + n0 + tx * 8) = o0;
      *(float4*)(C + (size_t)m * G4 + n0 + tx * 8 + 4) = o1;
    }
  }
}

// ---------------------------------------------------------------------------
// Kernel 2: zero the spread sync flags (64 arr lines + 16 done lines)
// ---------------------------------------------------------------------------
__global__ void k_zero(int* f) {
  for (int i = threadIdx.x; i < 2560; i += 256)
    __hip_atomic_store(&f[i], 0, __ATOMIC_RELAXED, __HIP_MEMORY_SCOPE_AGENT);
}

// ---------------------------------------------------------------------------
// Tree barrier, one cache line per writer (contention-free):
//  arrival: block b -> arr[b*32] = p        (64 parallel lines)
//  aggregate: block 0 wave 0 gathers arr (64-lane load over 64 lines),
//             then lane 0 replicates done=p onto 16 lines
//  wait: lane 0 polls done[(bid&15)*32]     (<=16 pollers per line)
// DEADLOCK FIX vs r9: block 0 must also aggregate the FINAL phase (TT+1)
// after its rnn loop — out blocks wait for done up to TT+1.
// ---------------------------------------------------------------------------
__device__ __forceinline__ void agg_phase(int* arr, int* done, int tid, int p) {
  if (tid < 64) {
    for (;;) {
      int v = __hip_atomic_load(&arr[tid * 32], __ATOMIC_RELAXED, __HIP_MEMORY_SCOPE_AGENT);
      if (__all(v >= p)) break;
      __builtin_amdgcn_s_sleep(1);
    }
    if (tid == 0) {
#pragma unroll
      for (int c = 0; c < 16; ++c)
        __hip_atomic_store(&done[c * 32], p, __ATOMIC_RELAXED, __HIP_MEMORY_SCOPE_AGENT);
    }
  }
}

__device__ __forceinline__ void tree_wait(int* arr, int* done, int bid, int tid, int p) {
  if (bid == 0) {
    agg_phase(arr, done, tid, p);
  } else if (tid == 0) {
    while (__hip_atomic_load(&done[(bid & 15) * 32], __ATOMIC_RELAXED,
                             __HIP_MEMORY_SCOPE_AGENT) < p)
      __builtin_amdgcn_s_sleep(1);
  }
  __syncthreads();
}

// ---------------------------------------------------------------------------
// Kernel 3: FUSED persistent recurrence + out-projection (r8 structure,
// contention-free sync, r9 deadlock fixed).
// Blocks 0..63 (rnn role): W_hh fp16 in LDS, 16 MFMA/step, gate_buf combine,
//   c in regs, packed-u32 agent-atomic h stores to hseq[s]; arrival to own
//   arr line; tree barrier; block 0 aggregates final phase TT+1 post-loop.
// Blocks 64..255 (out role): W_out slices in REGISTERS (preloaded once,
//   f32->f16); per step poll done >= s+1, stage h_s 64KB -> LDS (gload_lds,
//   inverse-swizzled source), LDS(h) x regs(W) MFMAs, float4 stores.
// ---------------------------------------------------------------------------
__global__ __launch_bounds__(512) void k_fused(const float* __restrict__ Gpre,
                                               const float* __restrict__ Whh,
                                               const float* __restrict__ Wout,
                                               const float* __restrict__ bout,
                                               char* hseq_base,
                                               float* __restrict__ out,
                                               int* __restrict__ flags) {
  __shared__ __align__(16) char lds_raw[65536];
  unsigned short* hseq16 = (unsigned short*)hseq_base;
  unsigned int* hseq32 = (unsigned int*)hseq_base;
  int* arr = flags;
  int* done = flags + 2048;

  const int tid = threadIdx.x;
  const int bid = blockIdx.x;
  const int l = tid & 63;
  const int w = tid >> 6;

  if (bid < 64) {
    // ======================= RNN role =======================
    unsigned short* W_lds = (unsigned short*)lds_raw;        // 32 KB
    float* gate_buf = (float*)(lds_raw + 32768);             // 8 KB
    const int u0 = bid * 8;
    const int lr = l & 15;
    const int kc = l >> 4;
    const int nt = w & 1;
    const int mt = w >> 1;
    const int es = w * 8 + (l >> 3);
    const int edu = l & 7;

    // stage W_hh (f32 -> fp16) into LDS, chunk-XOR swizzled
    {
      int row = tid >> 4;            // 0..31 (= g*8 + du)
      int sub = tid & 15;
      int g = row >> 3, du = row & 7;
      const float* srcp = Whh + (size_t)(g * 512 + u0 + du) * HH;
#pragma unroll
      for (int c0 = 0; c0 < 4; ++c0) {
        int c = sub * 4 + c0;
        float4 va = *(const float4*)(srcp + c * 8);
        float4 vb = *(const float4*)(srcp + c * 8 + 4);
        __align__(16) unsigned short t8[8];
        t8[0] = f2h(va.x); t8[1] = f2h(va.y); t8[2] = f2h(va.z); t8[3] = f2h(va.w);
        t8[4] = f2h(vb.x); t8[5] = f2h(vb.y); t8[6] = f2h(vb.z); t8[7] = f2h(vb.w);
        *(int4*)((char*)W_lds + row * 1024 + ((c ^ (row & 7)) * 16)) = *(const int4*)t8;
      }
    }

    // prime (h=c=0)
    float c_reg;
    {
      const float* gp = Gpre + (size_t)es * G4 + u0 + edu;
      float gi = gp[0], gg = gp[1024], go = gp[1536];
      float cn = sigm(gi) * tanh_fast(gg);
      float hn = sigm(go) * tanh_fast(cn);
      c_reg = cn;
      unsigned int hb = f2h(hn);
      unsigned int other = (unsigned int)__shfl_xor((int)hb, 1);
      if (!(l & 1))
        __hip_atomic_store(&hseq32[(size_t)es * 256 + bid * 4 + (edu >> 1)],
                           hb | (other << 16), __ATOMIC_RELAXED, __HIP_MEMORY_SCOPE_AGENT);
    }
    asm volatile("s_waitcnt vmcnt(0)" ::: "memory");
    __syncthreads();
    if (tid == 0)
      __hip_atomic_store(&arr[bid * 32], 1, __ATOMIC_RELAXED, __HIP_MEMORY_SCOPE_AGENT);

    float pre[4];
#pragma unroll
    for (int g = 0; g < 4; ++g)
      pre[g] = Gpre[((size_t)64 + es) * G4 + g * 512 + u0 + edu];

    tree_wait(arr, done, bid, tid, 1);

    for (int s = 1; s <= TT; ++s) {
      const unsigned short* hin = hseq16 + (size_t)(s - 1) * BB * HH;
      f32x4 acca = {0.f, 0.f, 0.f, 0.f};
      f32x4 accb = {0.f, 0.f, 0.f, 0.f};
      const unsigned short* hbase = hin + (size_t)(mt * 16 + lr) * HH + kc * 8;
      const int wrow = nt * 16 + lr;
      const char* wbase = (const char*)W_lds + wrow * 1024;
#pragma unroll
      for (int kk = 0; kk < 8; ++kk) {
        uint4 hq0 = *(const uint4*)(hbase + kk * 32);
        int4 wq0 = *(const int4*)(wbase + (((kk * 4 + kc) ^ (wrow & 7)) * 16));
        acca = __builtin_amdgcn_mfma_f32_16x16x32_f16(
            __builtin_bit_cast(f16x8, hq0), __builtin_bit_cast(f16x8, wq0), acca, 0, 0, 0);
        uint4 hq1 = *(const uint4*)(hbase + (kk + 8) * 32);
        int4 wq1 = *(const int4*)(wbase + ((((kk + 8) * 4 + kc) ^ (wrow & 7)) * 16));
        accb = __builtin_amdgcn_mfma_f32_16x16x32_f16(
            __builtin_bit_cast(f16x8, hq1), __builtin_bit_cast(f16x8, wq1), accb, 0, 0, 0);
      }
      f32x4 acc;
#pragma unroll
      for (int j = 0; j < 4; ++j) acc[j] = acca[j] + accb[j];

      // gate partials -> LDS (XOR-swizzled on sample index)
      {
        int g = nt * 2 + (lr >> 3);
        int du = lr & 7;
#pragma unroll
        for (int j = 0; j < 4; ++j) {
          int ss = mt * 16 + kc * 4 + j;
          gate_buf[g * 512 + du * 64 + (ss ^ (du << 3))] = acc[j];
        }
      }
      __syncthreads();

      // epilogue: one (es, edu) update per thread
      {
        float gi = gate_buf[0 * 512 + edu * 64 + (es ^ (edu << 3))] + pre[0];
        float gf = gate_buf[1 * 512 + edu * 64 + (es ^ (edu << 3))] + pre[1];
        float gg = gate_buf[2 * 512 + edu * 64 + (es ^ (edu << 3))] + pre[2];
        float go = gate_buf[3 * 512 + edu * 64 + (es ^ (edu << 3))] + pre[3];
        float cn = sigm(gf) * c_reg + sigm(gi) * tanh_fast(gg);
        float hn = sigm(go) * tanh_fast(cn);
        c_reg = cn;
        unsigned int hb = f2h(hn);
        unsigned int other = (unsigned int)__shfl_xor((int)hb, 1);
        if (!(l & 1))
          __hip_atomic_store(&hseq32[(size_t)s * 16384 + es * 256 + bid * 4 + (edu >> 1)],
                             hb | (other << 16), __ATOMIC_RELAXED, __HIP_MEMORY_SCOPE_AGENT);
      }
      asm volatile("s_waitcnt vmcnt(0)" ::: "memory");
      __syncthreads();
      if (tid == 0)
        __hip_atomic_store(&arr[bid * 32], s + 1, __ATOMIC_RELAXED, __HIP_MEMORY_SCOPE_AGENT);

      if (s < TT) {
#pragma unroll
        for (int g = 0; g < 4; ++g)
          pre[g] = Gpre[((size_t)(s + 1) * 64 + es) * G4 + g * 512 + u0 + edu];
        tree_wait(arr, done, bid, tid, s + 1);
      }
    }

    // FINAL aggregate (r9 deadlock fix): out blocks wait for done == TT+1.
    if (bid == 0) agg_phase(arr, done, tid, TT + 1);
  } else {
    // ======================= OUT role =======================
    unsigned short* As = (unsigned short*)lds_raw;           // 64 KB: h_s staged
    const int slice0 = bid - 64;           // 0..191
    const bool two = (slice0 < 58);        // +192 -> slices 192..249
    const int n00 = slice0 * 128;
    const int n01 = (two ? (slice0 + 192) : slice0) * 128;
    const int bcol = w * 16 + (l >> 4) * 4;
    const float4 bo0 = *(const float4*)(bout + n00 + bcol);
    const float4 bo1 = *(const float4*)(bout + n01 + bcol);

    // ---- preload W_out slice(s) f32 -> f16 fragments in REGISTERS (once) ----
    const int vr0 = n00 + w * 16 + (l & 15);
    const int vr1 = n01 + w * 16 + (l & 15);
    const int kb = (l >> 4) * 8;
    uint4 w0r[16], w1r[16];
#pragma unroll
    for (int kt = 0; kt < 16; ++kt) {
      const float* p = Wout + (size_t)vr0 * HH + kt * 32 + kb;
      float4 a = *(const float4*)p;
      float4 b = *(const float4*)(p + 4);
      __align__(16) unsigned short t8[8];
      t8[0] = f2h(a.x); t8[1] = f2h(a.y); t8[2] = f2h(a.z); t8[3] = f2h(a.w);
      t8[4] = f2h(b.x); t8[5] = f2h(b.y); t8[6] = f2h(b.z); t8[7] = f2h(b.w);
      w0r[kt] = *(const uint4*)t8;
    }
    if (two) {
#pragma unroll
      for (int kt = 0; kt < 16; ++kt) {
        const float* p = Wout + (size_t)vr1 * HH + kt * 32 + kb;
        float4 a = *(const float4*)p;
        float4 b = *(const float4*)(p + 4);
        __align__(16) unsigned short t8[8];
        t8[0] = f2h(a.x); t8[1] = f2h(a.y); t8[2] = f2h(a.z); t8[3] = f2h(a.w);
        t8[4] = f2h(b.x); t8[5] = f2h(b.y); t8[6] = f2h(b.z); t8[7] = f2h(b.w);
        w1r[kt] = *(const uint4*)t8;
      }
    }

    for (int s = 1; s <= TT; ++s) {
      if (tid == 0) {
        while (__hip_atomic_load(&done[(bid & 15) * 32], __ATOMIC_RELAXED,
                                 __HIP_MEMORY_SCOPE_AGENT) < s + 1)
          __builtin_amdgcn_s_sleep(2);
      }
      __syncthreads();   // release block; also guards As reuse from prev step

      // stage h_s (64 x 512 fp16 = 64 KB) -> LDS, inverse-swizzled source
      const unsigned short* hs = hseq16 + (size_t)s * BB * HH;
#pragma unroll
      for (int it = 0; it < 8; ++it) {
        int ci = it * 512 + tid;           // 16B-chunk index 0..4095
        int row = ci >> 6, cd = ci & 63;
        gload_lds16(hs + (size_t)row * 512 + (cd ^ (row & 7)) * 8, As + ci * 8);
      }
      asm volatile("s_waitcnt vmcnt(0)" ::: "memory");
      __syncthreads();

      f32x4 acc0[4], acc1[4];
#pragma unroll
      for (int m = 0; m < 4; ++m) {
        acc0[m] = (f32x4){0.f, 0.f, 0.f, 0.f};
        acc1[m] = (f32x4){0.f, 0.f, 0.f, 0.f};
      }
#pragma unroll
      for (int m = 0; m < 4; ++m) {
        int row = m * 16 + (l & 15);
#pragma unroll
        for (int kt = 0; kt < 16; ++kt) {
          int c = kt * 4 + (l >> 4);
          f16x8 af = *(const f16x8*)&As[row * 512 + (c ^ (row & 7)) * 8];
          // swapped operands: result col(lane&15) = h-row (sample),
          // row-field = W-row (vocab) -> lane stores 4 consecutive cols
          acc0[m] = __builtin_amdgcn_mfma_f32_16x16x32_f16(
              __builtin_bit_cast(f16x8, w0r[kt]), af, acc0[m], 0, 0, 0);
          if (two)
            acc1[m] = __builtin_amdgcn_mfma_f32_16x16x32_f16(
                __builtin_bit_cast(f16x8, w1r[kt]), af, acc1[m], 0, 0, 0);
        }
      }

#pragma unroll
      for (int m = 0; m < 4; ++m) {
        int b = m * 16 + (l & 15);
        float* orow0 = out + ((size_t)(b * TT + (s - 1))) * VV + n00 + bcol;
        float4 v;
        v.x = acc0[m][0] + bo0.x;
        v.y = acc0[m][1] + bo0.y;
        v.z = acc0[m][2] + bo0.z;
        v.w = acc0[m][3] + bo0.w;
        *(float4*)orow0 = v;
        if (two) {
          float* orow1 = out + ((size_t)(b * TT + (s - 1))) * VV + n01 + bcol;
          float4 v1;
          v1.x = acc1[m][0] + bo1.x;
          v1.y = acc1[m][1] + bo1.y;
          v1.z = acc1[m][2] + bo1.z;
          v1.w = acc1[m][3] + bo1.w;
          *(float4*)orow1 = v1;
        }
      }
    }
  }
}

// ---------------------------------------------------------------------------
extern "C" void kernel_launch(void* const* d_in, const int* in_sizes, int n_in,
                              void* d_out, int out_size, void* d_ws, size_t ws_size,
                              hipStream_t stream) {
  const float* feat = (const float*)d_in[0];
  const int* cap = (const int*)d_in[1];
  // d_in[2] = seq_len (constant 32)
  const float* emb = (const float*)d_in[3];
  const float* Wih = (const float*)d_in[4];
  const float* Whh = (const float*)d_in[5];
  const float* bih = (const float*)d_in[6];
  const float* bhh = (const float*)d_in[7];
  const float* Wout = (const float*)d_in[8];
  const float* bout = (const float*)d_in[9];
  float* out = (float*)d_out;

  char* ws = (char*)d_ws;
  float* Gpre = (float*)ws;                                   // 17,301,504
  char* hseq = ws + 17301504;                                 //  2,162,688 (33 x 64 x 512 fp16)
  int* flags = (int*)(ws + 19464192);                         //     10,240 (spread lines)

  k_zero<<<dim3(1), dim3(256), 0, stream>>>(flags);
  k_gemm_ih<<<dim3(17 * 16), dim3(256), 0, stream>>>(feat, cap, emb, Wih, bih, bhh, Gpre);
  k_fused<<<dim3(256), dim3(512), 0, stream>>>(Gpre, Whh, Wout, bout, hseq, out, flags);
}